// Round 1
// baseline (37.368 us; speedup 1.0000x reference)
//
#include <hip/hip_runtime.h>
#include <hip/hip_bf16.h>

#define N_FOODS 223
#define N_CATS 5
#define NPAIR (N_FOODS * N_CATS)   // 1115
#define NBATCH 1024
#define ELEMS 210                  // 7*3*10 per batch
#define FDIM 2

// Kernel A: F[v][c] = sum_i data[i][c] * exp(-100*(v - i*data[i][c])^2)
__global__ void build_table_kernel(const float* __restrict__ data,
                                   float* __restrict__ F) {
    int idx = blockIdx.x * blockDim.x + threadIdx.x;
    if (idx >= NPAIR) return;
    int v = idx / N_CATS;
    int c = idx - v * N_CATS;
    float x = (float)v;
    float s = 0.f;
    for (int i = 0; i < N_FOODS; ++i) {
        float val = data[i * N_CATS + c];
        float center = (float)i * val;
        float d = x - center;
        s += val * __expf(-100.f * d * d);
    }
    F[idx] = s;
}

// Kernel B: one block per batch row; table-lookup + reduce + atomicAdd.
__global__ __launch_bounds__(256) void loss_kernel(
    const float* __restrict__ y_pred, const float* __restrict__ y,
    const float* __restrict__ F, float* __restrict__ out) {
    __shared__ float Fs[NPAIR];
    __shared__ float red[4][2 * N_CATS];
    int tid = threadIdx.x;
    for (int i = tid; i < NPAIR; i += 256) Fs[i] = F[i];
    __syncthreads();

    int b = blockIdx.x;
    const float* yp = y_pred + (size_t)b * (ELEMS * FDIM);
    const float* yt = y      + (size_t)b * (ELEMS * FDIM);

    float acc[2 * N_CATS];
#pragma unroll
    for (int k = 0; k < 2 * N_CATS; ++k) acc[k] = 0.f;

    for (int e = tid; e < ELEMS; e += 256) {
        float t = yt[e * FDIM];            // exact integer 0..222
        int ti = (int)(t + 0.5f);
        float p = yp[e * FDIM];
        float r = rintf(p);                // round-half-even, matches jnp.round
        float z = 50.f * (222.5f - r);     // bound: r * sigmoid(z)
        float sig = 1.f / (1.f + __expf(-z));
        float pb = r * sig;                // == r exactly (r<=222) or ~3e-9 (r>=223)
        int pi = (int)rintf(pb);           // -> 0..222
#pragma unroll
        for (int c = 0; c < N_CATS; ++c) {
            acc[c]          += Fs[ti * N_CATS + c];
            acc[N_CATS + c] += Fs[pi * N_CATS + c];
        }
    }

    // wave(64)-level butterfly reduce for all 10 accumulators
#pragma unroll
    for (int k = 0; k < 2 * N_CATS; ++k) {
#pragma unroll
        for (int off = 32; off > 0; off >>= 1)
            acc[k] += __shfl_down(acc[k], off, 64);
    }
    int wave = tid >> 6;
    int lane = tid & 63;
    if (lane == 0) {
#pragma unroll
        for (int k = 0; k < 2 * N_CATS; ++k) red[wave][k] = acc[k];
    }
    __syncthreads();
    if (tid == 0) {
        float s = 0.f;
#pragma unroll
        for (int c = 0; c < N_CATS; ++c) {
            float g  = red[0][c] + red[1][c] + red[2][c] + red[3][c];
            float pr = red[0][N_CATS + c] + red[1][N_CATS + c] +
                       red[2][N_CATS + c] + red[3][N_CATS + c];
            s += fabsf(pr - g);
        }
        atomicAdd(out, s * (3.0f / (float)NBATCH));
    }
}

extern "C" void kernel_launch(void* const* d_in, const int* in_sizes, int n_in,
                              void* d_out, int out_size, void* d_ws, size_t ws_size,
                              hipStream_t stream) {
    const float* y_pred = (const float*)d_in[0];
    const float* y      = (const float*)d_in[1];
    const float* data   = (const float*)d_in[2];
    float* out = (float*)d_out;
    float* F   = (float*)d_ws;   // 1115 floats

    hipMemsetAsync(d_out, 0, sizeof(float), stream);
    build_table_kernel<<<(NPAIR + 255) / 256, 256, 0, stream>>>(data, F);
    loss_kernel<<<NBATCH, 256, 0, stream>>>(y_pred, y, F, out);
}

// Round 2
// 23.489 us; speedup vs baseline: 1.5909x; 1.5909x over previous
//
#include <hip/hip_runtime.h>
#include <hip/hip_bf16.h>

#define N_FOODS 223
#define N_CATS 5
#define NPAIR (N_FOODS * N_CATS)   // 1115
#define NBATCH 1024
#define ELEMS 210                  // 7*3*10 per batch
#define FDIM 2

// Kernel A: F[v][c] = sum_i data[i][c] * exp(-100*(v - i*data[i][c])^2)
// Also zero-inits the output accumulator (replaces a separate memset node).
__global__ void build_table_kernel(const float* __restrict__ data,
                                   float* __restrict__ F,
                                   float* __restrict__ out) {
    int idx = blockIdx.x * blockDim.x + threadIdx.x;
    if (idx == 0) out[0] = 0.f;
    if (idx >= NPAIR) return;
    int v = idx / N_CATS;
    int c = idx - v * N_CATS;
    float x = (float)v;
    float s = 0.f;
    for (int i = 0; i < N_FOODS; ++i) {
        float val = data[i * N_CATS + c];
        float center = (float)i * val;
        float d = x - center;
        s += val * __expf(-100.f * d * d);
    }
    F[idx] = s;
}

// Kernel B: one WAVE per batch row (4 rows per 256-thread block).
// Block-level LDS accumulation -> one global atomic per block (256 total).
__global__ __launch_bounds__(256) void loss_kernel(
    const float* __restrict__ y_pred, const float* __restrict__ y,
    const float* __restrict__ F, float* __restrict__ out) {
    __shared__ float Fs[NPAIR];
    __shared__ float bsum;
    int tid = threadIdx.x;
    if (tid == 0) bsum = 0.f;
    for (int i = tid; i < NPAIR; i += 256) Fs[i] = F[i];
    __syncthreads();

    int wave = tid >> 6;
    int lane = tid & 63;
    int b = blockIdx.x * 4 + wave;

    // stride-2 float arrays viewed as float2; field .x is the id channel
    const float2* yp = (const float2*)y_pred + (size_t)b * ELEMS;
    const float2* yt = (const float2*)y      + (size_t)b * ELEMS;

    float acc[2 * N_CATS];
#pragma unroll
    for (int k = 0; k < 2 * N_CATS; ++k) acc[k] = 0.f;

    for (int e = lane; e < ELEMS; e += 64) {
        float t = yt[e].x;                 // exact integer 0..222
        int ti = (int)(t + 0.5f);
        float p = yp[e].x;
        float r = rintf(p);                // round-half-even == jnp.round
        float z = 50.f * (222.5f - r);     // bound: r * sigmoid(z)
        float sig = 1.f / (1.f + __expf(-z));
        int pi = (int)rintf(r * sig);      // r (<=222) or 0 (>=223)
        const float* Ft = &Fs[ti * N_CATS];
        const float* Fp = &Fs[pi * N_CATS];
#pragma unroll
        for (int c = 0; c < N_CATS; ++c) {
            acc[c]          += Ft[c];
            acc[N_CATS + c] += Fp[c];
        }
    }

    // wave(64) butterfly reduce of the 10 per-batch sums
#pragma unroll
    for (int k = 0; k < 2 * N_CATS; ++k) {
#pragma unroll
        for (int off = 32; off > 0; off >>= 1)
            acc[k] += __shfl_down(acc[k], off, 64);
    }
    if (lane == 0) {
        float s = 0.f;
#pragma unroll
        for (int c = 0; c < N_CATS; ++c)
            s += fabsf(acc[N_CATS + c] - acc[c]);
        atomicAdd(&bsum, s);               // LDS atomic, cheap
    }
    __syncthreads();
    if (tid == 0)
        atomicAdd(out, bsum * (3.0f / (float)NBATCH));  // 256 global atomics
}

extern "C" void kernel_launch(void* const* d_in, const int* in_sizes, int n_in,
                              void* d_out, int out_size, void* d_ws, size_t ws_size,
                              hipStream_t stream) {
    const float* y_pred = (const float*)d_in[0];
    const float* y      = (const float*)d_in[1];
    const float* data   = (const float*)d_in[2];
    float* out = (float*)d_out;
    float* F   = (float*)d_ws;   // 1115 floats

    build_table_kernel<<<(NPAIR + 255) / 256, 256, 0, stream>>>(data, F, out);
    loss_kernel<<<NBATCH / 4, 256, 0, stream>>>(y_pred, y, F, out);
}